// Round 1
// baseline (53.649 us; speedup 1.0000x reference)
//
#include <hip/hip_runtime.h>
#include <hip/hip_bf16.h>
#include <stdint.h>

// Problem geometry
#define NB 64          // batch
#define NC 64          // C_IN
#define NU 2048        // N_UNITS
#define K_REAL 1296    // H*W = 36*36
#define K_PAD  1312    // 41*32, zero-padded K
#define M_ROWS 4096    // NB*NC

// GEMM tile
#define BM 128
#define BN 128
#define BK 32
#define NKT (K_PAD / BK)   // 41

typedef __attribute__((ext_vector_type(4))) float f32x4;
typedef __attribute__((ext_vector_type(8))) short bf16x8;

__device__ __forceinline__ unsigned short f2bf_rne(float f) {
  union { float f; uint32_t u; } v; v.f = f;
  uint32_t u = v.u;
  return (unsigned short)((u + 0x7FFFu + ((u >> 16) & 1u)) >> 16);
}

// Convert fp32 [rows][K_REAL] -> bf16 [rows][K_PAD], zero-filling the pad tail.
__global__ void convert_pad_kernel(const float* __restrict__ src,
                                   unsigned short* __restrict__ dst,
                                   int rows) {
  const int KB = K_PAD / 8;  // 164 8-element blocks per row
  int total = rows * KB;
  for (int idx = blockIdx.x * blockDim.x + threadIdx.x; idx < total;
       idx += gridDim.x * blockDim.x) {
    int r  = idx / KB;
    int kb = idx - r * KB;
    int k0 = kb * 8;
    uint32_t p0 = 0, p1 = 0, p2 = 0, p3 = 0;
    if (k0 + 8 <= K_REAL) {  // K_REAL % 8 == 0, so blocks are all-in or all-pad
      const float4* s = (const float4*)(src + (size_t)r * K_REAL + k0);
      float4 f0 = s[0];
      float4 f1 = s[1];
      p0 = (uint32_t)f2bf_rne(f0.x) | ((uint32_t)f2bf_rne(f0.y) << 16);
      p1 = (uint32_t)f2bf_rne(f0.z) | ((uint32_t)f2bf_rne(f0.w) << 16);
      p2 = (uint32_t)f2bf_rne(f1.x) | ((uint32_t)f2bf_rne(f1.y) << 16);
      p3 = (uint32_t)f2bf_rne(f1.z) | ((uint32_t)f2bf_rne(f1.w) << 16);
    }
    uint4 o; o.x = p0; o.y = p1; o.z = p2; o.w = p3;
    *(uint4*)(dst + (size_t)r * K_PAD + k0) = o;
  }
}

// Fused GEMM: G[(b,c),u] = sum_hw xbf[(b,c),hw] * swbf[u,hw]   (A·B^T, both K-major)
// epilogue: out[b,u] = sum_c fw[u,c]*G[(b,c),u] + bias[u]
// M-tile of 128 rows = 2 complete batches -> epilogue needs no atomics.
__global__ __launch_bounds__(256)
void fused_readout_gemm(const unsigned short* __restrict__ Abf,  // [M_ROWS][K_PAD]
                        const unsigned short* __restrict__ Bbf,  // [NU][K_PAD]
                        const float* __restrict__ fw,            // [NU][NC]
                        const float* __restrict__ bias,          // [NU]
                        float* __restrict__ out) {               // [NB][NU]
  __shared__ unsigned short As[BM * BK];
  __shared__ unsigned short Bs[BN * BK];

  const int tid  = threadIdx.x;
  const int lane = tid & 63;
  const int w    = tid >> 6;
  const int wr   = w >> 1;      // 0..1: which 64-row half (which batch)
  const int wc   = w & 1;       // 0..1: which 64-col half
  const int g    = lane >> 4;   // k-group 0..3
  const int rl   = lane & 15;

  const int tileM = (int)blockIdx.x >> 4;   // 0..31
  const int tileN = (int)blockIdx.x & 15;   // 0..15
  const int rowA0 = tileM * BM;
  const int colB0 = tileN * BN;

  f32x4 acc[4][4];
#pragma unroll
  for (int m = 0; m < 4; ++m)
#pragma unroll
    for (int n = 0; n < 4; ++n) acc[m][n] = (f32x4)0.f;

  for (int kt = 0; kt < NKT; ++kt) {
    const int k0 = kt * BK;
    // Stage A and B tiles: 8KB each = 512 chunks of 16B; 256 threads x 2 issues.
#pragma unroll
    for (int i = 0; i < 2; ++i) {
      const int ci  = i * 256 + tid;
      const int row = ci >> 2;        // 0..127
      const int kc  = ci & 3;         // which 8-elem chunk of the 32-wide K slab
      const unsigned short* ga = Abf + (size_t)(rowA0 + row) * K_PAD + k0 + kc * 8;
      __builtin_amdgcn_global_load_lds(
          (const __attribute__((address_space(1))) unsigned int*)(const void*)ga,
          (__attribute__((address_space(3))) unsigned int*)(void*)(As + ci * 8),
          16, 0, 0);
      const unsigned short* gb = Bbf + (size_t)(colB0 + row) * K_PAD + k0 + kc * 8;
      __builtin_amdgcn_global_load_lds(
          (const __attribute__((address_space(1))) unsigned int*)(const void*)gb,
          (__attribute__((address_space(3))) unsigned int*)(void*)(Bs + ci * 8),
          16, 0, 0);
    }
    __syncthreads();

    bf16x8 a[4], b[4];
#pragma unroll
    for (int m = 0; m < 4; ++m)
      a[m] = *(const bf16x8*)(As + (wr * 64 + m * 16 + rl) * BK + g * 8);
#pragma unroll
    for (int n = 0; n < 4; ++n)
      b[n] = *(const bf16x8*)(Bs + (wc * 64 + n * 16 + rl) * BK + g * 8);
#pragma unroll
    for (int m = 0; m < 4; ++m)
#pragma unroll
      for (int n = 0; n < 4; ++n)
        acc[m][n] = __builtin_amdgcn_mfma_f32_16x16x32_bf16(a[m], b[n], acc[m][n], 0, 0, 0);
    __syncthreads();
  }

  // Epilogue: weighted reduction over the wave's 64 rows (= c of one batch).
  // acc[m][n] element j is G at c = m*16 + g*4 + j, u = colB0 + wc*64 + n*16 + rl.
  const int bidx = tileM * 2 + wr;
  float val0, val1, val2, val3;
  float* vals[1]; (void)vals;
  float vtmp[4];
#pragma unroll
  for (int n = 0; n < 4; ++n) {
    const int u = colB0 + wc * 64 + n * 16 + rl;
    const float* fwrow = fw + (size_t)u * NC;
    float s = 0.f;
#pragma unroll
    for (int m = 0; m < 4; ++m) {
      float4 w4 = *(const float4*)(fwrow + m * 16 + g * 4);
      f32x4 av = acc[m][n];
      s += w4.x * av[0] + w4.y * av[1] + w4.z * av[2] + w4.w * av[3];
    }
    // reduce across the 4 k-groups (lanes xor 16, 32): lanes sharing (lane&15)
    s += __shfl_xor(s, 16, 64);
    s += __shfl_xor(s, 32, 64);
    vtmp[n] = s;
  }
  val0 = vtmp[0]; val1 = vtmp[1]; val2 = vtmp[2]; val3 = vtmp[3];

  // Write: lane l handles u = colB0 + wc*64 + l, value from n = l>>4 (static select).
  const int ucol = colB0 + wc * 64 + lane;
  float r = (g == 0) ? val0 : (g == 1) ? val1 : (g == 2) ? val2 : val3;
  out[(size_t)bidx * NU + ucol] = r + bias[ucol];
}

extern "C" void kernel_launch(void* const* d_in, const int* in_sizes, int n_in,
                              void* d_out, int out_size, void* d_ws, size_t ws_size,
                              hipStream_t stream) {
  const float* x    = (const float*)d_in[0];  // [64,64,36,36] = [4096][1296]
  const float* fw   = (const float*)d_in[1];  // [2048,64,1,1]
  const float* bias = (const float*)d_in[2];  // [2048]
  const float* sw   = (const float*)d_in[3];  // [2048,36,36] = [2048][1296]
  float* out = (float*)d_out;                 // [64][2048]

  unsigned short* Abf = (unsigned short*)d_ws;                       // 4096*1312*2 B
  unsigned short* Bbf = Abf + (size_t)M_ROWS * K_PAD;                // 2048*1312*2 B

  // Convert + zero-pad inputs to bf16 (K-major for gemm_bt)
  {
    int total = M_ROWS * (K_PAD / 8);
    int blocks = (total + 255) / 256;
    if (blocks > 2048) blocks = 2048;
    convert_pad_kernel<<<blocks, 256, 0, stream>>>(x, Abf, M_ROWS);
  }
  {
    int total = NU * (K_PAD / 8);
    int blocks = (total + 255) / 256;
    if (blocks > 2048) blocks = 2048;
    convert_pad_kernel<<<blocks, 256, 0, stream>>>(sw, Bbf, NU);
  }

  // Fused GEMM + readout: 32 M-tiles x 16 N-tiles
  fused_readout_gemm<<<dim3(32 * 16), 256, 0, stream>>>(Abf, Bbf, fw, bias, out);
}